// Round 1
// baseline (1023.560 us; speedup 1.0000x reference)
//
#include <hip/hip_runtime.h>

#define NN 100000
#define NE 1600000

// ---------------- degree + count histogram ----------------
__global__ __launch_bounds__(256) void k_deg_cnt(const int* __restrict__ dst,
    const float* __restrict__ ew, float* __restrict__ deg, int* __restrict__ cnt) {
  int e = blockIdx.x * 256 + threadIdx.x;
  if (e < NE) {
    int d = dst[e];
    atomicAdd(&deg[d], ew[e]);
    atomicAdd(&cnt[d], 1);
  }
}

__global__ __launch_bounds__(256) void k_dinv(float* d) {
  int i = blockIdx.x * 256 + threadIdx.x;
  if (i < NN) d[i] = rsqrtf(d[i] + 1.0f);
}

// ---------------- 3-kernel exclusive scan (counts -> indptr) ----------------
__global__ __launch_bounds__(256) void k_scan1(const int* __restrict__ cnt,
    int* __restrict__ indptr, int* __restrict__ bsum) {
  __shared__ int sd[256];
  int t = threadIdx.x, i = blockIdx.x * 256 + t;
  int v = (i < NN) ? cnt[i] : 0;
  sd[t] = v; __syncthreads();
  #pragma unroll
  for (int o = 1; o < 256; o <<= 1) {
    int x = (t >= o) ? sd[t - o] : 0;
    __syncthreads(); sd[t] += x; __syncthreads();
  }
  if (i < NN) indptr[i] = sd[t] - v;          // block-local exclusive
  if (t == 255) bsum[blockIdx.x] = sd[255];   // block total
}

__global__ __launch_bounds__(512) void k_scan2(const int* __restrict__ bsum,
    int* __restrict__ boff, int nb) {
  __shared__ int sd[512];
  int t = threadIdx.x;
  int v = (t < nb) ? bsum[t] : 0;
  sd[t] = v; __syncthreads();
  #pragma unroll
  for (int o = 1; o < 512; o <<= 1) {
    int x = (t >= o) ? sd[t - o] : 0;
    __syncthreads(); sd[t] += x; __syncthreads();
  }
  if (t < nb) boff[t] = sd[t] - v;            // exclusive block offsets
}

__global__ __launch_bounds__(256) void k_scan3(int* __restrict__ indptr,
    int* __restrict__ fill, const int* __restrict__ boff) {
  int i = blockIdx.x * 256 + threadIdx.x;
  if (i < NN) {
    int v = indptr[i] + boff[i >> 8];
    indptr[i] = v;
    fill[i] = v;                               // fill-cursor copy
  } else if (i == NN) {
    indptr[NN] = NE;
  }
}

// ---------------- CSR fill: edge id -> (src, coef) sorted by dst ----------------
__global__ __launch_bounds__(256) void k_fill(const int* __restrict__ src,
    const int* __restrict__ dst, const float* __restrict__ ew,
    const float* __restrict__ dinv, int* __restrict__ fill,
    int* __restrict__ esrc, float* __restrict__ ecoef) {
  int e = blockIdx.x * 256 + threadIdx.x;
  if (e < NE) {
    int s = src[e], d = dst[e];
    int p = atomicAdd(&fill[d], 1);
    esrc[p] = s;
    ecoef[p] = dinv[s] * dinv[d] * ew[e];      // coef computed once, reused 3x
  }
}

// ---------------- dense linear: out[N,64] = in[N,K] @ W[K,64] + b ----------------
// block=256 threads, ROWS=16*RPT rows/block; thread (tr,tc) computes RPT rows x 4 cols.
template<int K, int RPT>
__global__ __launch_bounds__(256) void k_lin(const float* __restrict__ in,
    const float* __restrict__ W, const float* __restrict__ bias,
    float* __restrict__ out) {
  constexpr int ROWS = 16 * RPT, RS = ROWS + 4;   // +4 pad: conflict-free reads, 8-way writes
  __shared__ __align__(16) float Wl[K * 64];
  __shared__ __align__(16) float rlT[K * RS];     // transposed row tile [k][r]
  __shared__ __align__(16) float bl[64];
  int t = threadIdx.x;
  int r0 = blockIdx.x * ROWS;
  for (int i = t; i < K * 64; i += 256) Wl[i] = W[i];
  if (t < 64) bl[t] = bias[t];
  for (int i = t; i < ROWS * K; i += 256) {       // coalesced global read
    int r = i / K, k = i - r * K;
    int row = r0 + r;
    rlT[k * RS + r] = (row < NN) ? in[(size_t)row * K + k] : 0.f;
  }
  __syncthreads();
  int tc = t & 15, tr = t >> 4;
  float4 bv = *(const float4*)&bl[tc * 4];
  float acc[RPT][4];
  #pragma unroll
  for (int j = 0; j < RPT; j++) { acc[j][0] = bv.x; acc[j][1] = bv.y; acc[j][2] = bv.z; acc[j][3] = bv.w; }
  for (int k = 0; k < K; k++) {
    float4 wv = *(const float4*)&Wl[k * 64 + tc * 4];
    float rv[RPT];
    if constexpr (RPT == 4) {
      float4 r4 = *(const float4*)&rlT[k * RS + tr * 4];
      rv[0] = r4.x; rv[1] = r4.y; rv[2] = r4.z; rv[3] = r4.w;
    } else {
      float2 r2 = *(const float2*)&rlT[k * RS + tr * 2];
      rv[0] = r2.x; rv[1] = r2.y;
    }
    #pragma unroll
    for (int j = 0; j < RPT; j++) {
      acc[j][0] += rv[j] * wv.x;
      acc[j][1] += rv[j] * wv.y;
      acc[j][2] += rv[j] * wv.z;
      acc[j][3] += rv[j] * wv.w;
    }
  }
  #pragma unroll
  for (int j = 0; j < RPT; j++) {
    int row = r0 + tr * RPT + j;
    if (row < NN) {
      float4 o = make_float4(acc[j][0], acc[j][1], acc[j][2], acc[j][3]);
      *(float4*)&out[(size_t)row * 64 + tc * 4] = o;
    }
  }
}

// ---------------- linz: cols 0..31 = in@Wmu+bmu, 32..63 = in@Wlv+blv ----------------
__global__ __launch_bounds__(256) void k_linz(const float* __restrict__ in,
    const float* __restrict__ Wmu, const float* __restrict__ bmu,
    const float* __restrict__ Wlv, const float* __restrict__ blv,
    float* __restrict__ out) {
  constexpr int K = 64, RPT = 4, ROWS = 64, RS = 68;
  __shared__ __align__(16) float Wl[K * 64];
  __shared__ __align__(16) float rlT[K * RS];
  __shared__ __align__(16) float bl[64];
  int t = threadIdx.x;
  int r0 = blockIdx.x * ROWS;
  for (int i = t; i < K * 64; i += 256) {
    int k = i >> 6, c = i & 63;
    Wl[i] = (c < 32) ? Wmu[k * 32 + c] : Wlv[k * 32 + c - 32];
  }
  if (t < 64) bl[t] = (t < 32) ? bmu[t] : blv[t - 32];
  for (int i = t; i < ROWS * K; i += 256) {
    int r = i / K, k = i - r * K;
    int row = r0 + r;
    rlT[k * RS + r] = (row < NN) ? in[(size_t)row * K + k] : 0.f;
  }
  __syncthreads();
  int tc = t & 15, tr = t >> 4;
  float4 bv = *(const float4*)&bl[tc * 4];
  float acc[RPT][4];
  #pragma unroll
  for (int j = 0; j < RPT; j++) { acc[j][0] = bv.x; acc[j][1] = bv.y; acc[j][2] = bv.z; acc[j][3] = bv.w; }
  for (int k = 0; k < K; k++) {
    float4 wv = *(const float4*)&Wl[k * 64 + tc * 4];
    float4 r4 = *(const float4*)&rlT[k * RS + tr * 4];
    float rv[4] = { r4.x, r4.y, r4.z, r4.w };
    #pragma unroll
    for (int j = 0; j < RPT; j++) {
      acc[j][0] += rv[j] * wv.x;
      acc[j][1] += rv[j] * wv.y;
      acc[j][2] += rv[j] * wv.z;
      acc[j][3] += rv[j] * wv.w;
    }
  }
  #pragma unroll
  for (int j = 0; j < RPT; j++) {
    int row = r0 + tr * RPT + j;
    if (row < NN) {
      float4 o = make_float4(acc[j][0], acc[j][1], acc[j][2], acc[j][3]);
      *(float4*)&out[(size_t)row * 64 + tc * 4] = o;
    }
  }
}

// ---------------- CSR gather: out[i] = sum_e coef*h[src] + dinv_i^2 * h[i] ----------------
// one wave per dst node, lane = feature
template<bool FINAL>
__global__ __launch_bounds__(256) void k_gather(const float* __restrict__ h,
    const float* __restrict__ dinv, const int* __restrict__ indptr,
    const int* __restrict__ esrc, const float* __restrict__ ecoef,
    float* __restrict__ out) {
  int wid = (blockIdx.x * 256 + threadIdx.x) >> 6;
  int lane = threadIdx.x & 63;
  if (wid >= NN) return;
  int i = wid;
  int e0 = indptr[i], e1 = indptr[i + 1];
  float di = dinv[i];
  float acc = h[(size_t)i * 64 + lane] * (di * di);   // self-loop term
  for (int e = e0; e < e1; e++) {
    int s = esrc[e];
    float cf = ecoef[e];
    acc += h[(size_t)s * 64 + lane] * cf;
  }
  if (!FINAL) {
    out[(size_t)i * 64 + lane] = acc;
  } else {
    if (lane < 32) out[(size_t)i * 32 + lane] = acc;                       // mu
    else out[(size_t)NN * 32 + (size_t)i * 32 + (lane - 32)] = acc;        // logvar
  }
}

// ---------------- batch-norm stats (S1, S2 per column) ----------------
__global__ __launch_bounds__(256) void k_bnstats(const float* __restrict__ h,
    float* __restrict__ stats) {
  __shared__ float s1[256], s2[256];
  int t = threadIdx.x, c = t & 63, rg = t >> 6;
  float a1 = 0.f, a2 = 0.f;
  for (int row = blockIdx.x * 4 + rg; row < NN; row += gridDim.x * 4) {
    float v = h[(size_t)row * 64 + c];
    a1 += v; a2 += v * v;
  }
  s1[t] = a1; s2[t] = a2; __syncthreads();
  if (rg == 0) {
    a1 = s1[c] + s1[64 + c] + s1[128 + c] + s1[192 + c];
    a2 = s2[c] + s2[64 + c] + s2[128 + c] + s2[192 + c];
    atomicAdd(&stats[c], a1);
    atomicAdd(&stats[64 + c], a2);
  }
}

// ---------------- batch-norm apply + ReLU, in place ----------------
__global__ __launch_bounds__(256) void k_bnapply(float* __restrict__ h,
    const float* __restrict__ stats, const float* __restrict__ g,
    const float* __restrict__ be) {
  int idx = blockIdx.x * 256 + threadIdx.x;
  if (idx >= NN * 64) return;
  int c = idx & 63;
  const float invn = 1.0f / (float)NN;
  float m = stats[c] * invn;
  float v = stats[64 + c] * invn - m * m;
  float x = (h[idx] - m) * rsqrtf(v + 1e-5f) * g[c] + be[c];
  h[idx] = x > 0.f ? x : 0.f;
}

extern "C" void kernel_launch(void* const* d_in, const int* in_sizes, int n_in,
                              void* d_out, int out_size, void* d_ws, size_t ws_size,
                              hipStream_t stream) {
  (void)in_sizes; (void)n_in; (void)out_size; (void)ws_size;
  const float* x    = (const float*)d_in[0];
  const int*   ei   = (const int*)d_in[1];
  const float* ew   = (const float*)d_in[2];
  const float* W_in = (const float*)d_in[3];
  const float* b_in = (const float*)d_in[4];
  const float* W1   = (const float*)d_in[5];
  const float* b1   = (const float*)d_in[6];
  const float* W2   = (const float*)d_in[7];
  const float* b2   = (const float*)d_in[8];
  const float* Wmu  = (const float*)d_in[9];
  const float* bmu  = (const float*)d_in[10];
  const float* Wlv  = (const float*)d_in[11];
  const float* blv  = (const float*)d_in[12];
  const float* g1   = (const float*)d_in[13];
  const float* be1  = (const float*)d_in[14];
  const float* g2   = (const float*)d_in[15];
  const float* be2  = (const float*)d_in[16];
  const int* src = ei;
  const int* dst = ei + NE;
  float* out = (float*)d_out;

  // workspace carve-up (256B aligned slices)
  char* p = (char*)d_ws;
  auto carve = [&](size_t bytes) { void* r = (void*)p; p += (bytes + 255) & ~(size_t)255; return r; };
  float* A      = (float*)carve((size_t)NN * 64 * 4);
  float* B      = (float*)carve((size_t)NN * 64 * 4);
  float* dinv   = (float*)carve((size_t)NN * 4);       // deg then in-place rsqrt
  int*   cnt    = (int*)carve((size_t)NN * 4);
  int*   indptr = (int*)carve((size_t)(NN + 1) * 4);
  int*   fill   = (int*)carve((size_t)NN * 4);
  int*   esrc   = (int*)carve((size_t)NE * 4);
  float* ecoef  = (float*)carve((size_t)NE * 4);
  int*   bsum   = (int*)carve(512 * 4);
  int*   boff   = (int*)carve(512 * 4);
  float* stats  = (float*)carve(128 * 4);

  const int nbE = (NE + 255) / 256;     // 6250
  const int nbN = (NN + 255) / 256;     // 391
  const int gLin128 = (NN + 31) / 32;   // 3125
  const int gLin64  = (NN + 63) / 64;   // 1563
  const int gWave   = (NN + 3) / 4;     // 25000 (4 waves/block, 1 node/wave)
  const int gElem   = (NN * 64) / 256;  // 25000

  // ---- graph preprocessing (identical every call) ----
  hipMemsetAsync(dinv, 0, (size_t)NN * 4, stream);
  hipMemsetAsync(cnt, 0, (size_t)NN * 4, stream);
  k_deg_cnt<<<nbE, 256, 0, stream>>>(dst, ew, dinv, cnt);
  k_dinv<<<nbN, 256, 0, stream>>>(dinv);
  k_scan1<<<nbN, 256, 0, stream>>>(cnt, indptr, bsum);
  k_scan2<<<1, 512, 0, stream>>>(bsum, boff, nbN);
  k_scan3<<<nbN, 256, 0, stream>>>(indptr, fill, boff);
  k_fill<<<nbE, 256, 0, stream>>>(src, dst, ew, dinv, fill, esrc, ecoef);

  // ---- h0 = x @ W_in + b_in ----
  k_lin<128, 2><<<gLin128, 256, 0, stream>>>(x, W_in, b_in, A);
  // ---- conv1 ----
  k_lin<64, 4><<<gLin64, 256, 0, stream>>>(A, W1, b1, B);
  k_gather<false><<<gWave, 256, 0, stream>>>(B, dinv, indptr, esrc, ecoef, A);
  hipMemsetAsync(stats, 0, 128 * 4, stream);
  k_bnstats<<<256, 256, 0, stream>>>(A, stats);
  k_bnapply<<<gElem, 256, 0, stream>>>(A, stats, g1, be1);
  // ---- conv2 ----
  k_lin<64, 4><<<gLin64, 256, 0, stream>>>(A, W2, b2, B);
  k_gather<false><<<gWave, 256, 0, stream>>>(B, dinv, indptr, esrc, ecoef, A);
  hipMemsetAsync(stats, 0, 128 * 4, stream);
  k_bnstats<<<256, 256, 0, stream>>>(A, stats);
  k_bnapply<<<gElem, 256, 0, stream>>>(A, stats, g2, be2);
  // ---- mu / logvar (fused 64-wide payload) ----
  k_linz<<<gLin64, 256, 0, stream>>>(A, Wmu, bmu, Wlv, blv, B);
  k_gather<true><<<gWave, 256, 0, stream>>>(B, dinv, indptr, esrc, ecoef, out);
}

// Round 4
// 762.352 us; speedup vs baseline: 1.3426x; 1.3426x over previous
//
#include <hip/hip_runtime.h>

#define NN 100000
#define NE 1600000

// ---------------- degree + count histogram ----------------
__global__ __launch_bounds__(256) void k_deg_cnt(const int* __restrict__ dst,
    const float* __restrict__ ew, float* __restrict__ deg, int* __restrict__ cnt) {
  int e = blockIdx.x * 256 + threadIdx.x;
  if (e < NE) {
    int d = dst[e];
    atomicAdd(&deg[d], ew[e]);
    atomicAdd(&cnt[d], 1);
  }
}

__global__ __launch_bounds__(256) void k_dinv(float* d) {
  int i = blockIdx.x * 256 + threadIdx.x;
  if (i < NN) d[i] = rsqrtf(d[i] + 1.0f);
}

// ---------------- 3-kernel exclusive scan (counts -> indptr) ----------------
__global__ __launch_bounds__(256) void k_scan1(const int* __restrict__ cnt,
    int* __restrict__ indptr, int* __restrict__ bsum) {
  __shared__ int sd[256];
  int t = threadIdx.x, i = blockIdx.x * 256 + t;
  int v = (i < NN) ? cnt[i] : 0;
  sd[t] = v; __syncthreads();
  #pragma unroll
  for (int o = 1; o < 256; o <<= 1) {
    int x = (t >= o) ? sd[t - o] : 0;
    __syncthreads(); sd[t] += x; __syncthreads();
  }
  if (i < NN) indptr[i] = sd[t] - v;          // block-local exclusive
  if (t == 255) bsum[blockIdx.x] = sd[255];   // block total
}

__global__ __launch_bounds__(512) void k_scan2(const int* __restrict__ bsum,
    int* __restrict__ boff, int nb) {
  __shared__ int sd[512];
  int t = threadIdx.x;
  int v = (t < nb) ? bsum[t] : 0;
  sd[t] = v; __syncthreads();
  #pragma unroll
  for (int o = 1; o < 512; o <<= 1) {
    int x = (t >= o) ? sd[t - o] : 0;
    __syncthreads(); sd[t] += x; __syncthreads();
  }
  if (t < nb) boff[t] = sd[t] - v;            // exclusive block offsets
}

__global__ __launch_bounds__(256) void k_scan3(int* __restrict__ indptr,
    int* __restrict__ fill, const int* __restrict__ boff) {
  int i = blockIdx.x * 256 + threadIdx.x;
  if (i < NN) {
    int v = indptr[i] + boff[i >> 8];
    indptr[i] = v;
    fill[i] = v;                               // fill-cursor copy
  } else if (i == NN) {
    indptr[NN] = NE;
  }
}

// ---------------- CSR fill: edge id -> packed (src, coef) record sorted by dst ----------------
__global__ __launch_bounds__(256) void k_fill(const int* __restrict__ src,
    const int* __restrict__ dst, const float* __restrict__ ew,
    const float* __restrict__ dinv, int* __restrict__ fill,
    int2* __restrict__ edges) {
  int e = blockIdx.x * 256 + threadIdx.x;
  if (e < NE) {
    int s = src[e], d = dst[e];
    int p = atomicAdd(&fill[d], 1);
    float coef = dinv[s] * dinv[d] * ew[e];    // coef computed once, reused 3x
    edges[p] = make_int2(s, __float_as_int(coef));  // single 8B scattered write
  }
}

// ---------------- dense linear: out[N,64] = f(in)[N,K] @ W[K,64] + b ----------------
// BN=true: f(x) = relu(x*scale[c]+shift[c]) with scale/shift from raw column stats.
// block=256 threads, ROWS=16*RPT rows/block; thread (tr,tc) computes RPT rows x 4 cols.
template<int K, int RPT, bool BN>
__global__ __launch_bounds__(256) void k_lin(const float* __restrict__ in,
    const float* __restrict__ W, const float* __restrict__ bias,
    const float* __restrict__ stats, const float* __restrict__ g,
    const float* __restrict__ be, float* __restrict__ out) {
  constexpr int ROWS = 16 * RPT, RS = ROWS + 4;   // +4 pad: conflict-free reads, 8-way writes
  __shared__ __align__(16) float Wl[K * 64];
  __shared__ __align__(16) float rlT[K * RS];     // transposed row tile [k][r]
  __shared__ __align__(16) float bl[64];
  __shared__ float bnscale[BN ? K : 1], bnshift[BN ? K : 1];
  int t = threadIdx.x;
  int r0 = blockIdx.x * ROWS;
  for (int i = t; i < K * 64; i += 256) Wl[i] = W[i];
  if (t < 64) bl[t] = bias[t];
  if constexpr (BN) {
    if (t < K) {
      const float invn = 1.0f / (float)NN;
      float m = stats[t] * invn;
      float v = stats[64 + t] * invn - m * m;
      float sc = g[t] * rsqrtf(v + 1e-5f);
      bnscale[t] = sc;
      bnshift[t] = be[t] - m * sc;
    }
    __syncthreads();
  }
  for (int i = t; i < ROWS * K; i += 256) {       // coalesced global read
    int r = i / K, k = i - r * K;
    int row = r0 + r;
    float v = (row < NN) ? in[(size_t)row * K + k] : 0.f;
    if constexpr (BN) {
      v = v * bnscale[k] + bnshift[k];
      v = v > 0.f ? v : 0.f;
    }
    rlT[k * RS + r] = v;
  }
  __syncthreads();
  int tc = t & 15, tr = t >> 4;
  float4 bv = *(const float4*)&bl[tc * 4];
  float acc[RPT][4];
  #pragma unroll
  for (int j = 0; j < RPT; j++) { acc[j][0] = bv.x; acc[j][1] = bv.y; acc[j][2] = bv.z; acc[j][3] = bv.w; }
  for (int k = 0; k < K; k++) {
    float4 wv = *(const float4*)&Wl[k * 64 + tc * 4];
    float rv[RPT];
    if constexpr (RPT == 4) {
      float4 r4 = *(const float4*)&rlT[k * RS + tr * 4];
      rv[0] = r4.x; rv[1] = r4.y; rv[2] = r4.z; rv[3] = r4.w;
    } else {
      float2 r2 = *(const float2*)&rlT[k * RS + tr * 2];
      rv[0] = r2.x; rv[1] = r2.y;
    }
    #pragma unroll
    for (int j = 0; j < RPT; j++) {
      acc[j][0] += rv[j] * wv.x;
      acc[j][1] += rv[j] * wv.y;
      acc[j][2] += rv[j] * wv.z;
      acc[j][3] += rv[j] * wv.w;
    }
  }
  #pragma unroll
  for (int j = 0; j < RPT; j++) {
    int row = r0 + tr * RPT + j;
    if (row < NN) {
      float4 o = make_float4(acc[j][0], acc[j][1], acc[j][2], acc[j][3]);
      *(float4*)&out[(size_t)row * 64 + tc * 4] = o;
    }
  }
}

// ---------------- linz: cols 0..31 = f(in)@Wmu+bmu, 32..63 = f(in)@Wlv+blv ----------------
// f = relu(bn2(.)) fused from raw stats
__global__ __launch_bounds__(256) void k_linz(const float* __restrict__ in,
    const float* __restrict__ Wmu, const float* __restrict__ bmu,
    const float* __restrict__ Wlv, const float* __restrict__ blv,
    const float* __restrict__ stats, const float* __restrict__ g,
    const float* __restrict__ be, float* __restrict__ out) {
  constexpr int K = 64, RPT = 4, ROWS = 64, RS = 68;
  __shared__ __align__(16) float Wl[K * 64];
  __shared__ __align__(16) float rlT[K * RS];
  __shared__ __align__(16) float bl[64];
  __shared__ float bnscale[K], bnshift[K];
  int t = threadIdx.x;
  int r0 = blockIdx.x * ROWS;
  for (int i = t; i < K * 64; i += 256) {
    int k = i >> 6, c = i & 63;
    Wl[i] = (c < 32) ? Wmu[k * 32 + c] : Wlv[k * 32 + c - 32];
  }
  if (t < 64) bl[t] = (t < 32) ? bmu[t] : blv[t - 32];
  if (t < K) {
    const float invn = 1.0f / (float)NN;
    float m = stats[t] * invn;
    float v = stats[64 + t] * invn - m * m;
    float sc = g[t] * rsqrtf(v + 1e-5f);
    bnscale[t] = sc;
    bnshift[t] = be[t] - m * sc;
  }
  __syncthreads();
  for (int i = t; i < ROWS * K; i += 256) {
    int r = i / K, k = i - r * K;
    int row = r0 + r;
    float v = (row < NN) ? in[(size_t)row * K + k] : 0.f;
    v = v * bnscale[k] + bnshift[k];
    rlT[k * RS + r] = v > 0.f ? v : 0.f;
  }
  __syncthreads();
  int tc = t & 15, tr = t >> 4;
  float4 bv = *(const float4*)&bl[tc * 4];
  float acc[RPT][4];
  #pragma unroll
  for (int j = 0; j < RPT; j++) { acc[j][0] = bv.x; acc[j][1] = bv.y; acc[j][2] = bv.z; acc[j][3] = bv.w; }
  for (int k = 0; k < K; k++) {
    float4 wv = *(const float4*)&Wl[k * 64 + tc * 4];
    float4 r4 = *(const float4*)&rlT[k * RS + tr * 4];
    float rv[4] = { r4.x, r4.y, r4.z, r4.w };
    #pragma unroll
    for (int j = 0; j < RPT; j++) {
      acc[j][0] += rv[j] * wv.x;
      acc[j][1] += rv[j] * wv.y;
      acc[j][2] += rv[j] * wv.z;
      acc[j][3] += rv[j] * wv.w;
    }
  }
  #pragma unroll
  for (int j = 0; j < RPT; j++) {
    int row = r0 + tr * RPT + j;
    if (row < NN) {
      float4 o = make_float4(acc[j][0], acc[j][1], acc[j][2], acc[j][3]);
      *(float4*)&out[(size_t)row * 64 + tc * 4] = o;
    }
  }
}

// ---------------- CSR gather: out[i] = sum_e coef*h[src] + dinv_i^2 * h[i] ----------------
// one wave per dst node, lane = feature; edge loop unrolled x4 for MLP
template<bool FINAL>
__global__ __launch_bounds__(256) void k_gather(const float* __restrict__ h,
    const float* __restrict__ dinv, const int* __restrict__ indptr,
    const int2* __restrict__ edges, float* __restrict__ out) {
  int wid = (blockIdx.x * 256 + threadIdx.x) >> 6;
  int lane = threadIdx.x & 63;
  if (wid >= NN) return;
  int i = wid;
  int e0 = indptr[i], e1 = indptr[i + 1];
  float di = dinv[i];
  float acc = h[(size_t)i * 64 + lane] * (di * di);   // self-loop term
  int e = e0;
  for (; e + 4 <= e1; e += 4) {
    int2 r0 = edges[e];
    int2 r1 = edges[e + 1];
    int2 r2 = edges[e + 2];
    int2 r3 = edges[e + 3];
    float v0 = h[(size_t)r0.x * 64 + lane];
    float v1 = h[(size_t)r1.x * 64 + lane];
    float v2 = h[(size_t)r2.x * 64 + lane];
    float v3 = h[(size_t)r3.x * 64 + lane];
    acc += v0 * __int_as_float(r0.y);
    acc += v1 * __int_as_float(r1.y);
    acc += v2 * __int_as_float(r2.y);
    acc += v3 * __int_as_float(r3.y);
  }
  for (; e < e1; e++) {
    int2 r = edges[e];
    acc += h[(size_t)r.x * 64 + lane] * __int_as_float(r.y);
  }
  if (!FINAL) {
    out[(size_t)i * 64 + lane] = acc;
  } else {
    if (lane < 32) out[(size_t)i * 32 + lane] = acc;                       // mu
    else out[(size_t)NN * 32 + (size_t)i * 32 + (lane - 32)] = acc;        // logvar
  }
}

// ---------------- batch-norm stats (S1, S2 per column of raw conv output) ----------------
__global__ __launch_bounds__(256) void k_bnstats(const float* __restrict__ h,
    float* __restrict__ stats) {
  __shared__ float s1[256], s2[256];
  int t = threadIdx.x, c = t & 63, rg = t >> 6;
  float a1 = 0.f, a2 = 0.f;
  for (int row = blockIdx.x * 4 + rg; row < NN; row += gridDim.x * 4) {
    float v = h[(size_t)row * 64 + c];
    a1 += v; a2 += v * v;
  }
  s1[t] = a1; s2[t] = a2; __syncthreads();
  if (rg == 0) {
    a1 = s1[c] + s1[64 + c] + s1[128 + c] + s1[192 + c];
    a2 = s2[c] + s2[64 + c] + s2[128 + c] + s2[192 + c];
    atomicAdd(&stats[c], a1);
    atomicAdd(&stats[64 + c], a2);
  }
}

extern "C" void kernel_launch(void* const* d_in, const int* in_sizes, int n_in,
                              void* d_out, int out_size, void* d_ws, size_t ws_size,
                              hipStream_t stream) {
  (void)in_sizes; (void)n_in; (void)out_size; (void)ws_size;
  const float* x    = (const float*)d_in[0];
  const int*   ei   = (const int*)d_in[1];
  const float* ew   = (const float*)d_in[2];
  const float* W_in = (const float*)d_in[3];
  const float* b_in = (const float*)d_in[4];
  const float* W1   = (const float*)d_in[5];
  const float* b1   = (const float*)d_in[6];
  const float* W2   = (const float*)d_in[7];
  const float* b2   = (const float*)d_in[8];
  const float* Wmu  = (const float*)d_in[9];
  const float* bmu  = (const float*)d_in[10];
  const float* Wlv  = (const float*)d_in[11];
  const float* blv  = (const float*)d_in[12];
  const float* g1   = (const float*)d_in[13];
  const float* be1  = (const float*)d_in[14];
  const float* g2   = (const float*)d_in[15];
  const float* be2  = (const float*)d_in[16];
  const int* src = ei;
  const int* dst = ei + NE;
  float* out = (float*)d_out;

  // workspace carve-up (256B aligned slices)
  char* p = (char*)d_ws;
  auto carve = [&](size_t bytes) { void* r = (void*)p; p += (bytes + 255) & ~(size_t)255; return r; };
  float* A      = (float*)carve((size_t)NN * 64 * 4);
  float* B      = (float*)carve((size_t)NN * 64 * 4);
  float* dinv   = (float*)carve((size_t)NN * 4);       // deg then in-place rsqrt
  int*   cnt    = (int*)carve((size_t)NN * 4);
  int*   indptr = (int*)carve((size_t)(NN + 1) * 4);
  int*   fill   = (int*)carve((size_t)NN * 4);
  int2*  edges  = (int2*)carve((size_t)NE * 8);        // packed (src, coef)
  int*   bsum   = (int*)carve(512 * 4);
  int*   boff   = (int*)carve(512 * 4);
  float* stats1 = (float*)carve(128 * 4);
  float* stats2 = (float*)carve(128 * 4);

  const int nbE = (NE + 255) / 256;     // 6250
  const int nbN = (NN + 255) / 256;     // 391
  const int gLin128 = (NN + 31) / 32;   // 3125
  const int gLin64  = (NN + 63) / 64;   // 1563
  const int gWave   = (NN + 3) / 4;     // 25000 (4 waves/block, 1 node/wave)

  // ---- graph preprocessing (identical every call) ----
  hipMemsetAsync(dinv, 0, (size_t)NN * 4, stream);
  hipMemsetAsync(cnt, 0, (size_t)NN * 4, stream);
  k_deg_cnt<<<nbE, 256, 0, stream>>>(dst, ew, dinv, cnt);
  k_dinv<<<nbN, 256, 0, stream>>>(dinv);
  k_scan1<<<nbN, 256, 0, stream>>>(cnt, indptr, bsum);
  k_scan2<<<1, 512, 0, stream>>>(bsum, boff, nbN);
  k_scan3<<<nbN, 256, 0, stream>>>(indptr, fill, boff);
  k_fill<<<nbE, 256, 0, stream>>>(src, dst, ew, dinv, fill, edges);

  // ---- h0 = x @ W_in + b_in ----
  k_lin<128, 2, false><<<gLin128, 256, 0, stream>>>(x, W_in, b_in, nullptr, nullptr, nullptr, A);
  // ---- conv1 ----
  k_lin<64, 4, false><<<gLin64, 256, 0, stream>>>(A, W1, b1, nullptr, nullptr, nullptr, B);
  k_gather<false><<<gWave, 256, 0, stream>>>(B, dinv, indptr, edges, A);
  hipMemsetAsync(stats1, 0, 128 * 4, stream);
  k_bnstats<<<256, 256, 0, stream>>>(A, stats1);
  // ---- conv2 (BN1+ReLU fused into lin's staging) ----
  k_lin<64, 4, true><<<gLin64, 256, 0, stream>>>(A, W2, b2, stats1, g1, be1, B);
  k_gather<false><<<gWave, 256, 0, stream>>>(B, dinv, indptr, edges, A);
  hipMemsetAsync(stats2, 0, 128 * 4, stream);
  k_bnstats<<<256, 256, 0, stream>>>(A, stats2);
  // ---- mu / logvar (BN2+ReLU fused, 64-wide payload) ----
  k_linz<<<gLin64, 256, 0, stream>>>(A, Wmu, bmu, Wlv, blv, stats2, g2, be2, B);
  k_gather<true><<<gWave, 256, 0, stream>>>(B, dinv, indptr, edges, out);
}

// Round 5
// 671.277 us; speedup vs baseline: 1.5248x; 1.1357x over previous
//
#include <hip/hip_runtime.h>

#define NN 100000
#define NE 1600000

// ---------------- packed degree+count histogram: one u64 atomic per edge ----------------
// rec = (1 << 40) | fixed24(ew);  count in bits [40,64), deg sum in 24.24 fixed point.
__global__ __launch_bounds__(256) void k_degpack(const int* __restrict__ dst,
    const float* __restrict__ ew, unsigned long long* __restrict__ packed) {
  int e = blockIdx.x * 256 + threadIdx.x;
  if (e < NE) {
    int d = dst[e];
    unsigned long long rec = (1ULL << 40) |
        (unsigned long long)__float2uint_rn(ew[e] * 16777216.0f);
    atomicAdd(&packed[d], rec);
  }
}

__global__ __launch_bounds__(256) void k_unpack(const unsigned long long* __restrict__ packed,
    float* __restrict__ dinv, int* __restrict__ cnt) {
  int i = blockIdx.x * 256 + threadIdx.x;
  if (i < NN) {
    unsigned long long v = packed[i];
    cnt[i] = (int)(v >> 40);
    float deg = (float)(v & ((1ULL << 40) - 1)) * (1.0f / 16777216.0f);
    dinv[i] = rsqrtf(deg + 1.0f);
  }
}

// ---------------- 3-kernel exclusive scan (counts -> indptr) ----------------
__global__ __launch_bounds__(256) void k_scan1(const int* __restrict__ cnt,
    int* __restrict__ indptr, int* __restrict__ bsum) {
  __shared__ int sd[256];
  int t = threadIdx.x, i = blockIdx.x * 256 + t;
  int v = (i < NN) ? cnt[i] : 0;
  sd[t] = v; __syncthreads();
  #pragma unroll
  for (int o = 1; o < 256; o <<= 1) {
    int x = (t >= o) ? sd[t - o] : 0;
    __syncthreads(); sd[t] += x; __syncthreads();
  }
  if (i < NN) indptr[i] = sd[t] - v;          // block-local exclusive
  if (t == 255) bsum[blockIdx.x] = sd[255];   // block total
}

__global__ __launch_bounds__(512) void k_scan2(const int* __restrict__ bsum,
    int* __restrict__ boff, int nb) {
  __shared__ int sd[512];
  int t = threadIdx.x;
  int v = (t < nb) ? bsum[t] : 0;
  sd[t] = v; __syncthreads();
  #pragma unroll
  for (int o = 1; o < 512; o <<= 1) {
    int x = (t >= o) ? sd[t - o] : 0;
    __syncthreads(); sd[t] += x; __syncthreads();
  }
  if (t < nb) boff[t] = sd[t] - v;            // exclusive block offsets
}

__global__ __launch_bounds__(256) void k_scan3(int* __restrict__ indptr,
    int* __restrict__ fill, const int* __restrict__ boff) {
  int i = blockIdx.x * 256 + threadIdx.x;
  if (i < NN) {
    int v = indptr[i] + boff[i >> 8];
    indptr[i] = v;
    fill[i] = v;                               // fill-cursor copy
  } else if (i == NN) {
    indptr[NN] = NE;
  }
}

// ---------------- CSR fill: edge id -> packed (src, coef) record sorted by dst ----------------
__global__ __launch_bounds__(256) void k_fill(const int* __restrict__ src,
    const int* __restrict__ dst, const float* __restrict__ ew,
    const float* __restrict__ dinv, int* __restrict__ fill,
    int2* __restrict__ edges) {
  int e = blockIdx.x * 256 + threadIdx.x;
  if (e < NE) {
    int s = src[e], d = dst[e];
    int p = atomicAdd(&fill[d], 1);
    float coef = dinv[s] * dinv[d] * ew[e];    // coef computed once, reused 3x
    edges[p] = make_int2(s, __float_as_int(coef));  // single 8B scattered write
  }
}

// ---------------- dense linear: out[N,64] = f(in)[N,K] @ W[K,64] + b ----------------
// BN=true: f(x) = relu(x*scale[c]+shift[c]) with scale/shift from raw column stats.
template<int K, int RPT, bool BN>
__global__ __launch_bounds__(256) void k_lin(const float* __restrict__ in,
    const float* __restrict__ W, const float* __restrict__ bias,
    const float* __restrict__ stats, const float* __restrict__ g,
    const float* __restrict__ be, float* __restrict__ out) {
  constexpr int ROWS = 16 * RPT, RS = ROWS + 4;   // +4 pad: conflict-free reads, 8-way writes
  __shared__ __align__(16) float Wl[K * 64];
  __shared__ __align__(16) float rlT[K * RS];     // transposed row tile [k][r]
  __shared__ __align__(16) float bl[64];
  __shared__ float bnscale[BN ? K : 1], bnshift[BN ? K : 1];
  int t = threadIdx.x;
  int r0 = blockIdx.x * ROWS;
  for (int i = t; i < K * 64; i += 256) Wl[i] = W[i];
  if (t < 64) bl[t] = bias[t];
  if constexpr (BN) {
    if (t < K) {
      const float invn = 1.0f / (float)NN;
      float m = stats[t] * invn;
      float v = stats[64 + t] * invn - m * m;
      float sc = g[t] * rsqrtf(v + 1e-5f);
      bnscale[t] = sc;
      bnshift[t] = be[t] - m * sc;
    }
    __syncthreads();
  }
  for (int i = t; i < ROWS * K; i += 256) {       // coalesced global read
    int r = i / K, k = i - r * K;
    int row = r0 + r;
    float v = (row < NN) ? in[(size_t)row * K + k] : 0.f;
    if constexpr (BN) {
      v = v * bnscale[k] + bnshift[k];
      v = v > 0.f ? v : 0.f;
    }
    rlT[k * RS + r] = v;
  }
  __syncthreads();
  int tc = t & 15, tr = t >> 4;
  float4 bv = *(const float4*)&bl[tc * 4];
  float acc[RPT][4];
  #pragma unroll
  for (int j = 0; j < RPT; j++) { acc[j][0] = bv.x; acc[j][1] = bv.y; acc[j][2] = bv.z; acc[j][3] = bv.w; }
  for (int k = 0; k < K; k++) {
    float4 wv = *(const float4*)&Wl[k * 64 + tc * 4];
    float rv[RPT];
    if constexpr (RPT == 4) {
      float4 r4 = *(const float4*)&rlT[k * RS + tr * 4];
      rv[0] = r4.x; rv[1] = r4.y; rv[2] = r4.z; rv[3] = r4.w;
    } else {
      float2 r2 = *(const float2*)&rlT[k * RS + tr * 2];
      rv[0] = r2.x; rv[1] = r2.y;
    }
    #pragma unroll
    for (int j = 0; j < RPT; j++) {
      acc[j][0] += rv[j] * wv.x;
      acc[j][1] += rv[j] * wv.y;
      acc[j][2] += rv[j] * wv.z;
      acc[j][3] += rv[j] * wv.w;
    }
  }
  #pragma unroll
  for (int j = 0; j < RPT; j++) {
    int row = r0 + tr * RPT + j;
    if (row < NN) {
      float4 o = make_float4(acc[j][0], acc[j][1], acc[j][2], acc[j][3]);
      *(float4*)&out[(size_t)row * 64 + tc * 4] = o;
    }
  }
}

// ---------------- linz: cols 0..31 = f(in)@Wmu+bmu, 32..63 = f(in)@Wlv+blv ----------------
__global__ __launch_bounds__(256) void k_linz(const float* __restrict__ in,
    const float* __restrict__ Wmu, const float* __restrict__ bmu,
    const float* __restrict__ Wlv, const float* __restrict__ blv,
    const float* __restrict__ stats, const float* __restrict__ g,
    const float* __restrict__ be, float* __restrict__ out) {
  constexpr int K = 64, RPT = 4, ROWS = 64, RS = 68;
  __shared__ __align__(16) float Wl[K * 64];
  __shared__ __align__(16) float rlT[K * RS];
  __shared__ __align__(16) float bl[64];
  __shared__ float bnscale[K], bnshift[K];
  int t = threadIdx.x;
  int r0 = blockIdx.x * ROWS;
  for (int i = t; i < K * 64; i += 256) {
    int k = i >> 6, c = i & 63;
    Wl[i] = (c < 32) ? Wmu[k * 32 + c] : Wlv[k * 32 + c - 32];
  }
  if (t < 64) bl[t] = (t < 32) ? bmu[t] : blv[t - 32];
  if (t < K) {
    const float invn = 1.0f / (float)NN;
    float m = stats[t] * invn;
    float v = stats[64 + t] * invn - m * m;
    float sc = g[t] * rsqrtf(v + 1e-5f);
    bnscale[t] = sc;
    bnshift[t] = be[t] - m * sc;
  }
  __syncthreads();
  for (int i = t; i < ROWS * K; i += 256) {
    int r = i / K, k = i - r * K;
    int row = r0 + r;
    float v = (row < NN) ? in[(size_t)row * K + k] : 0.f;
    v = v * bnscale[k] + bnshift[k];
    rlT[k * RS + r] = v > 0.f ? v : 0.f;
  }
  __syncthreads();
  int tc = t & 15, tr = t >> 4;
  float4 bv = *(const float4*)&bl[tc * 4];
  float acc[RPT][4];
  #pragma unroll
  for (int j = 0; j < RPT; j++) { acc[j][0] = bv.x; acc[j][1] = bv.y; acc[j][2] = bv.z; acc[j][3] = bv.w; }
  for (int k = 0; k < K; k++) {
    float4 wv = *(const float4*)&Wl[k * 64 + tc * 4];
    float4 r4 = *(const float4*)&rlT[k * RS + tr * 4];
    float rv[4] = { r4.x, r4.y, r4.z, r4.w };
    #pragma unroll
    for (int j = 0; j < RPT; j++) {
      acc[j][0] += rv[j] * wv.x;
      acc[j][1] += rv[j] * wv.y;
      acc[j][2] += rv[j] * wv.z;
      acc[j][3] += rv[j] * wv.w;
    }
  }
  #pragma unroll
  for (int j = 0; j < RPT; j++) {
    int row = r0 + tr * RPT + j;
    if (row < NN) {
      float4 o = make_float4(acc[j][0], acc[j][1], acc[j][2], acc[j][3]);
      *(float4*)&out[(size_t)row * 64 + tc * 4] = o;
    }
  }
}

// ---------------- CSR gather, 2 nodes per wave, float2 lanes ----------------
// lanes 0-31 -> node 2w, lanes 32-63 -> node 2w+1; each lane owns 2 features.
template<bool FINAL>
__global__ __launch_bounds__(256) void k_gather2(const float2* __restrict__ h,
    const float* __restrict__ dinv, const int* __restrict__ indptr,
    const int2* __restrict__ edges, float* __restrict__ out) {
  int wid = (blockIdx.x * 256 + threadIdx.x) >> 6;
  int lane = threadIdx.x & 63;
  int half = lane >> 5, sub = lane & 31;
  int i = wid * 2 + half;                      // dst node for this half-wave
  if (i >= NN) return;
  int e0 = indptr[i], e1 = indptr[i + 1];
  float di = dinv[i];
  float2 hv = h[(size_t)i * 32 + sub];
  float2 acc = make_float2(hv.x * di * di, hv.y * di * di);   // self-loop term
  int e = e0;
  for (; e + 4 <= e1; e += 4) {
    int2 r0 = edges[e];
    int2 r1 = edges[e + 1];
    int2 r2 = edges[e + 2];
    int2 r3 = edges[e + 3];
    float2 v0 = h[(size_t)r0.x * 32 + sub];
    float2 v1 = h[(size_t)r1.x * 32 + sub];
    float2 v2 = h[(size_t)r2.x * 32 + sub];
    float2 v3 = h[(size_t)r3.x * 32 + sub];
    float c0 = __int_as_float(r0.y), c1 = __int_as_float(r1.y);
    float c2 = __int_as_float(r2.y), c3 = __int_as_float(r3.y);
    acc.x += v0.x * c0; acc.y += v0.y * c0;
    acc.x += v1.x * c1; acc.y += v1.y * c1;
    acc.x += v2.x * c2; acc.y += v2.y * c2;
    acc.x += v3.x * c3; acc.y += v3.y * c3;
  }
  for (; e < e1; e++) {
    int2 r = edges[e];
    float2 v = h[(size_t)r.x * 32 + sub];
    float c = __int_as_float(r.y);
    acc.x += v.x * c; acc.y += v.y * c;
  }
  if (!FINAL) {
    *(float2*)&out[(size_t)i * 64 + sub * 2] = acc;
  } else {
    int c0 = sub * 2;
    if (sub < 16) {                                            // mu cols 0..31
      *(float2*)&out[(size_t)i * 32 + c0] = acc;
    } else {                                                   // logvar cols 32..63
      *(float2*)&out[(size_t)NN * 32 + (size_t)i * 32 + (c0 - 32)] = acc;
    }
  }
}

// ---------------- batch-norm stats (S1, S2 per column of raw conv output) ----------------
__global__ __launch_bounds__(256) void k_bnstats(const float* __restrict__ h,
    float* __restrict__ stats) {
  __shared__ float s1[256], s2[256];
  int t = threadIdx.x, c = t & 63, rg = t >> 6;
  float a1 = 0.f, a2 = 0.f;
  for (int row = blockIdx.x * 4 + rg; row < NN; row += gridDim.x * 4) {
    float v = h[(size_t)row * 64 + c];
    a1 += v; a2 += v * v;
  }
  s1[t] = a1; s2[t] = a2; __syncthreads();
  if (rg == 0) {
    a1 = s1[c] + s1[64 + c] + s1[128 + c] + s1[192 + c];
    a2 = s2[c] + s2[64 + c] + s2[128 + c] + s2[192 + c];
    atomicAdd(&stats[c], a1);
    atomicAdd(&stats[64 + c], a2);
  }
}

extern "C" void kernel_launch(void* const* d_in, const int* in_sizes, int n_in,
                              void* d_out, int out_size, void* d_ws, size_t ws_size,
                              hipStream_t stream) {
  (void)in_sizes; (void)n_in; (void)out_size; (void)ws_size;
  const float* x    = (const float*)d_in[0];
  const int*   ei   = (const int*)d_in[1];
  const float* ew   = (const float*)d_in[2];
  const float* W_in = (const float*)d_in[3];
  const float* b_in = (const float*)d_in[4];
  const float* W1   = (const float*)d_in[5];
  const float* b1   = (const float*)d_in[6];
  const float* W2   = (const float*)d_in[7];
  const float* b2   = (const float*)d_in[8];
  const float* Wmu  = (const float*)d_in[9];
  const float* bmu  = (const float*)d_in[10];
  const float* Wlv  = (const float*)d_in[11];
  const float* blv  = (const float*)d_in[12];
  const float* g1   = (const float*)d_in[13];
  const float* be1  = (const float*)d_in[14];
  const float* g2   = (const float*)d_in[15];
  const float* be2  = (const float*)d_in[16];
  const int* src = ei;
  const int* dst = ei + NE;
  float* out = (float*)d_out;

  // workspace carve-up (256B aligned slices)
  char* p = (char*)d_ws;
  auto carve = [&](size_t bytes) { void* r = (void*)p; p += (bytes + 255) & ~(size_t)255; return r; };
  float* A      = (float*)carve((size_t)NN * 64 * 4);
  float* B      = (float*)carve((size_t)NN * 64 * 4);
  unsigned long long* packed = (unsigned long long*)carve((size_t)NN * 8);
  float* dinv   = (float*)carve((size_t)NN * 4);
  int*   cnt    = (int*)carve((size_t)NN * 4);
  int*   indptr = (int*)carve((size_t)(NN + 1) * 4);
  int*   fill   = (int*)carve((size_t)NN * 4);
  int2*  edges  = (int2*)carve((size_t)NE * 8);        // packed (src, coef)
  int*   bsum   = (int*)carve(512 * 4);
  int*   boff   = (int*)carve(512 * 4);
  float* stats1 = (float*)carve(128 * 4);
  float* stats2 = (float*)carve(128 * 4);

  const int nbE = (NE + 255) / 256;     // 6250
  const int nbN = (NN + 255) / 256;     // 391
  const int gLin128 = (NN + 31) / 32;   // 3125
  const int gLin64  = (NN + 63) / 64;   // 1563
  const int gWave2  = ((NN + 1) / 2 * 64 + 255) / 256;  // 12500 (2 nodes/wave)

  // ---- graph preprocessing (identical every call) ----
  hipMemsetAsync(packed, 0, (size_t)NN * 8, stream);
  k_degpack<<<nbE, 256, 0, stream>>>(dst, ew, packed);
  k_unpack<<<nbN, 256, 0, stream>>>(packed, dinv, cnt);
  k_scan1<<<nbN, 256, 0, stream>>>(cnt, indptr, bsum);
  k_scan2<<<1, 512, 0, stream>>>(bsum, boff, nbN);
  k_scan3<<<nbN, 256, 0, stream>>>(indptr, fill, boff);
  k_fill<<<nbE, 256, 0, stream>>>(src, dst, ew, dinv, fill, edges);

  // ---- h0 = x @ W_in + b_in ----
  k_lin<128, 2, false><<<gLin128, 256, 0, stream>>>(x, W_in, b_in, nullptr, nullptr, nullptr, A);
  // ---- conv1 ----
  k_lin<64, 4, false><<<gLin64, 256, 0, stream>>>(A, W1, b1, nullptr, nullptr, nullptr, B);
  k_gather2<false><<<gWave2, 256, 0, stream>>>((const float2*)B, dinv, indptr, edges, A);
  hipMemsetAsync(stats1, 0, 128 * 4, stream);
  k_bnstats<<<256, 256, 0, stream>>>(A, stats1);
  // ---- conv2 (BN1+ReLU fused into lin's staging) ----
  k_lin<64, 4, true><<<gLin64, 256, 0, stream>>>(A, W2, b2, stats1, g1, be1, B);
  k_gather2<false><<<gWave2, 256, 0, stream>>>((const float2*)B, dinv, indptr, edges, A);
  hipMemsetAsync(stats2, 0, 128 * 4, stream);
  k_bnstats<<<256, 256, 0, stream>>>(A, stats2);
  // ---- mu / logvar (BN2+ReLU fused, 64-wide payload) ----
  k_linz<<<gLin64, 256, 0, stream>>>(A, Wmu, bmu, Wlv, blv, stats2, g2, be2, B);
  k_gather2<true><<<gWave2, 256, 0, stream>>>((const float2*)B, dinv, indptr, edges, out);
}

// Round 9
// 612.533 us; speedup vs baseline: 1.6710x; 1.0959x over previous
//
#include <hip/hip_runtime.h>

#define NN 100000
#define NE 1600000

// ---------------- packed degree+count histogram: one returning u64 atomic per edge ----
// rec = (1 << 40) | fixed24(ew); count in bits [40,64), deg sum in 24.24 fixed point.
// The returned old count field is this edge's rank within its dst segment.
__global__ __launch_bounds__(256) void k_degpack(const int* __restrict__ dst,
    const float* __restrict__ ew, unsigned long long* __restrict__ packed,
    unsigned char* __restrict__ rank) {
  int e = blockIdx.x * 256 + threadIdx.x;
  if (e < NE) {
    int d = dst[e];
    unsigned long long rec = (1ULL << 40) |
        (unsigned long long)__float2uint_rn(ew[e] * 16777216.0f);
    unsigned long long old = atomicAdd(&packed[d], rec);
    rank[e] = (unsigned char)(old >> 40);
  }
}

__global__ __launch_bounds__(256) void k_unpack(const unsigned long long* __restrict__ packed,
    float* __restrict__ dinv, int* __restrict__ cnt) {
  int i = blockIdx.x * 256 + threadIdx.x;
  if (i < NN) {
    unsigned long long v = packed[i];
    cnt[i] = (int)(v >> 40);
    float deg = (float)(v & ((1ULL << 40) - 1)) * (1.0f / 16777216.0f);
    dinv[i] = rsqrtf(deg + 1.0f);
  }
}

// ---------------- 3-kernel exclusive scan (counts -> indptr) ----------------
__global__ __launch_bounds__(256) void k_scan1(const int* __restrict__ cnt,
    int* __restrict__ indptr, int* __restrict__ bsum) {
  __shared__ int sd[256];
  int t = threadIdx.x, i = blockIdx.x * 256 + t;
  int v = (i < NN) ? cnt[i] : 0;
  sd[t] = v; __syncthreads();
  #pragma unroll
  for (int o = 1; o < 256; o <<= 1) {
    int x = (t >= o) ? sd[t - o] : 0;
    __syncthreads(); sd[t] += x; __syncthreads();
  }
  if (i < NN) indptr[i] = sd[t] - v;          // block-local exclusive
  if (t == 255) bsum[blockIdx.x] = sd[255];   // block total
}

__global__ __launch_bounds__(512) void k_scan2(const int* __restrict__ bsum,
    int* __restrict__ boff, int nb) {
  __shared__ int sd[512];
  int t = threadIdx.x;
  int v = (t < nb) ? bsum[t] : 0;
  sd[t] = v; __syncthreads();
  #pragma unroll
  for (int o = 1; o < 512; o <<= 1) {
    int x = (t >= o) ? sd[t - o] : 0;
    __syncthreads(); sd[t] += x; __syncthreads();
  }
  if (t < nb) boff[t] = sd[t] - v;            // exclusive block offsets
}

__global__ __launch_bounds__(256) void k_scan3(int* __restrict__ indptr,
    const int* __restrict__ boff) {
  int i = blockIdx.x * 256 + threadIdx.x;
  if (i < NN) {
    indptr[i] = indptr[i] + boff[i >> 8];
  } else if (i == NN) {
    indptr[NN] = NE;
  }
}

// ---------------- CSR fill: deterministic position, NO atomics ----------------
__global__ __launch_bounds__(256) void k_fill(const int* __restrict__ src,
    const int* __restrict__ dst, const float* __restrict__ ew,
    const float* __restrict__ dinv, const int* __restrict__ indptr,
    const unsigned char* __restrict__ rank, int2* __restrict__ edges) {
  int e = blockIdx.x * 256 + threadIdx.x;
  if (e < NE) {
    int s = src[e], d = dst[e];
    int p = indptr[d] + (int)rank[e];
    float coef = dinv[s] * dinv[d] * ew[e];    // coef computed once, reused 3x
    edges[p] = make_int2(s, __float_as_int(coef));  // single 8B scattered write
  }
}

// ---------------- dense linear: out[N,64] = f(in)[N,K] @ W[K,64] + b ----------------
// BN=true: f(x) = relu(x*scale[c]+shift[c]) with scale/shift from raw column stats.
template<int K, int RPT, bool BN>
__global__ __launch_bounds__(256) void k_lin(const float* __restrict__ in,
    const float* __restrict__ W, const float* __restrict__ bias,
    const float* __restrict__ stats, const float* __restrict__ g,
    const float* __restrict__ be, float* __restrict__ out) {
  constexpr int ROWS = 16 * RPT, RS = ROWS + 4;   // +4 pad: conflict-free reads, 8-way writes
  __shared__ __align__(16) float Wl[K * 64];
  __shared__ __align__(16) float rlT[K * RS];     // transposed row tile [k][r]
  __shared__ __align__(16) float bl[64];
  __shared__ float bnscale[BN ? K : 1], bnshift[BN ? K : 1];
  int t = threadIdx.x;
  int r0 = blockIdx.x * ROWS;
  for (int i = t; i < K * 64; i += 256) Wl[i] = W[i];
  if (t < 64) bl[t] = bias[t];
  if constexpr (BN) {
    if (t < K) {
      const float invn = 1.0f / (float)NN;
      float m = stats[t] * invn;
      float v = stats[64 + t] * invn - m * m;
      float sc = g[t] * rsqrtf(v + 1e-5f);
      bnscale[t] = sc;
      bnshift[t] = be[t] - m * sc;
    }
    __syncthreads();
  }
  for (int i = t; i < ROWS * K; i += 256) {       // coalesced global read
    int r = i / K, k = i - r * K;
    int row = r0 + r;
    float v = (row < NN) ? in[(size_t)row * K + k] : 0.f;
    if constexpr (BN) {
      v = v * bnscale[k] + bnshift[k];
      v = v > 0.f ? v : 0.f;
    }
    rlT[k * RS + r] = v;
  }
  __syncthreads();
  int tc = t & 15, tr = t >> 4;
  float4 bv = *(const float4*)&bl[tc * 4];
  float acc[RPT][4];
  #pragma unroll
  for (int j = 0; j < RPT; j++) { acc[j][0] = bv.x; acc[j][1] = bv.y; acc[j][2] = bv.z; acc[j][3] = bv.w; }
  for (int k = 0; k < K; k++) {
    float4 wv = *(const float4*)&Wl[k * 64 + tc * 4];
    float rv[RPT];
    if constexpr (RPT == 4) {
      float4 r4 = *(const float4*)&rlT[k * RS + tr * 4];
      rv[0] = r4.x; rv[1] = r4.y; rv[2] = r4.z; rv[3] = r4.w;
    } else {
      float2 r2 = *(const float2*)&rlT[k * RS + tr * 2];
      rv[0] = r2.x; rv[1] = r2.y;
    }
    #pragma unroll
    for (int j = 0; j < RPT; j++) {
      acc[j][0] += rv[j] * wv.x;
      acc[j][1] += rv[j] * wv.y;
      acc[j][2] += rv[j] * wv.z;
      acc[j][3] += rv[j] * wv.w;
    }
  }
  #pragma unroll
  for (int j = 0; j < RPT; j++) {
    int row = r0 + tr * RPT + j;
    if (row < NN) {
      float4 o = make_float4(acc[j][0], acc[j][1], acc[j][2], acc[j][3]);
      *(float4*)&out[(size_t)row * 64 + tc * 4] = o;
    }
  }
}

// ---------------- linz: cols 0..31 = f(in)@Wmu+bmu, 32..63 = f(in)@Wlv+blv ----------------
__global__ __launch_bounds__(256) void k_linz(const float* __restrict__ in,
    const float* __restrict__ Wmu, const float* __restrict__ bmu,
    const float* __restrict__ Wlv, const float* __restrict__ blv,
    const float* __restrict__ stats, const float* __restrict__ g,
    const float* __restrict__ be, float* __restrict__ out) {
  constexpr int K = 64, RPT = 4, ROWS = 64, RS = 68;
  __shared__ __align__(16) float Wl[K * 64];
  __shared__ __align__(16) float rlT[K * RS];
  __shared__ __align__(16) float bl[64];
  __shared__ float bnscale[K], bnshift[K];
  int t = threadIdx.x;
  int r0 = blockIdx.x * ROWS;
  for (int i = t; i < K * 64; i += 256) {
    int k = i >> 6, c = i & 63;
    Wl[i] = (c < 32) ? Wmu[k * 32 + c] : Wlv[k * 32 + c - 32];
  }
  if (t < 64) bl[t] = (t < 32) ? bmu[t] : blv[t - 32];
  if (t < K) {
    const float invn = 1.0f / (float)NN;
    float m = stats[t] * invn;
    float v = stats[64 + t] * invn - m * m;
    float sc = g[t] * rsqrtf(v + 1e-5f);
    bnscale[t] = sc;
    bnshift[t] = be[t] - m * sc;
  }
  __syncthreads();
  for (int i = t; i < ROWS * K; i += 256) {
    int r = i / K, k = i - r * K;
    int row = r0 + r;
    float v = (row < NN) ? in[(size_t)row * K + k] : 0.f;
    v = v * bnscale[k] + bnshift[k];
    rlT[k * RS + r] = v > 0.f ? v : 0.f;
  }
  __syncthreads();
  int tc = t & 15, tr = t >> 4;
  float4 bv = *(const float4*)&bl[tc * 4];
  float acc[RPT][4];
  #pragma unroll
  for (int j = 0; j < RPT; j++) { acc[j][0] = bv.x; acc[j][1] = bv.y; acc[j][2] = bv.z; acc[j][3] = bv.w; }
  for (int k = 0; k < K; k++) {
    float4 wv = *(const float4*)&Wl[k * 64 + tc * 4];
    float4 r4 = *(const float4*)&rlT[k * RS + tr * 4];
    float rv[4] = { r4.x, r4.y, r4.z, r4.w };
    #pragma unroll
    for (int j = 0; j < RPT; j++) {
      acc[j][0] += rv[j] * wv.x;
      acc[j][1] += rv[j] * wv.y;
      acc[j][2] += rv[j] * wv.z;
      acc[j][3] += rv[j] * wv.w;
    }
  }
  #pragma unroll
  for (int j = 0; j < RPT; j++) {
    int row = r0 + tr * RPT + j;
    if (row < NN) {
      float4 o = make_float4(acc[j][0], acc[j][1], acc[j][2], acc[j][3]);
      *(float4*)&out[(size_t)row * 64 + tc * 4] = o;
    }
  }
}

// ---------------- CSR gather, 2 nodes per wave, float2 lanes, unroll x8 ----------------
// lanes 0-31 -> node 2w, lanes 32-63 -> node 2w+1; each lane owns 2 features.
template<bool FINAL>
__global__ __launch_bounds__(256) void k_gather2(const float2* __restrict__ h,
    const float* __restrict__ dinv, const int* __restrict__ indptr,
    const int2* __restrict__ edges, float* __restrict__ out) {
  int wid = (blockIdx.x * 256 + threadIdx.x) >> 6;
  int lane = threadIdx.x & 63;
  int half = lane >> 5, sub = lane & 31;
  int i = wid * 2 + half;                      // dst node for this half-wave
  if (i >= NN) return;
  int e0 = indptr[i], e1 = indptr[i + 1];
  float di = dinv[i];
  float2 hv = h[(size_t)i * 32 + sub];
  float2 acc = make_float2(hv.x * di * di, hv.y * di * di);   // self-loop term
  int e = e0;
  for (; e + 8 <= e1; e += 8) {
    int2 r0 = edges[e];
    int2 r1 = edges[e + 1];
    int2 r2 = edges[e + 2];
    int2 r3 = edges[e + 3];
    int2 r4 = edges[e + 4];
    int2 r5 = edges[e + 5];
    int2 r6 = edges[e + 6];
    int2 r7 = edges[e + 7];
    float2 v0 = h[(size_t)r0.x * 32 + sub];
    float2 v1 = h[(size_t)r1.x * 32 + sub];
    float2 v2 = h[(size_t)r2.x * 32 + sub];
    float2 v3 = h[(size_t)r3.x * 32 + sub];
    float2 v4 = h[(size_t)r4.x * 32 + sub];
    float2 v5 = h[(size_t)r5.x * 32 + sub];
    float2 v6 = h[(size_t)r6.x * 32 + sub];
    float2 v7 = h[(size_t)r7.x * 32 + sub];
    float c0 = __int_as_float(r0.y), c1 = __int_as_float(r1.y);
    float c2 = __int_as_float(r2.y), c3 = __int_as_float(r3.y);
    float c4 = __int_as_float(r4.y), c5 = __int_as_float(r5.y);
    float c6 = __int_as_float(r6.y), c7 = __int_as_float(r7.y);
    acc.x += v0.x * c0; acc.y += v0.y * c0;
    acc.x += v1.x * c1; acc.y += v1.y * c1;
    acc.x += v2.x * c2; acc.y += v2.y * c2;
    acc.x += v3.x * c3; acc.y += v3.y * c3;
    acc.x += v4.x * c4; acc.y += v4.y * c4;
    acc.x += v5.x * c5; acc.y += v5.y * c5;
    acc.x += v6.x * c6; acc.y += v6.y * c6;
    acc.x += v7.x * c7; acc.y += v7.y * c7;
  }
  for (; e + 2 <= e1; e += 2) {
    int2 ra = edges[e];
    int2 rb = edges[e + 1];
    float2 va = h[(size_t)ra.x * 32 + sub];
    float2 vb = h[(size_t)rb.x * 32 + sub];
    float ca = __int_as_float(ra.y), cb = __int_as_float(rb.y);
    acc.x += va.x * ca; acc.y += va.y * ca;
    acc.x += vb.x * cb; acc.y += vb.y * cb;
  }
  if (e < e1) {
    int2 r = edges[e];
    float2 v = h[(size_t)r.x * 32 + sub];
    float c = __int_as_float(r.y);
    acc.x += v.x * c; acc.y += v.y * c;
  }
  if (!FINAL) {
    *(float2*)&out[(size_t)i * 64 + sub * 2] = acc;
  } else {
    int c0 = sub * 2;
    if (sub < 16) {                                            // mu cols 0..31
      *(float2*)&out[(size_t)i * 32 + c0] = acc;
    } else {                                                   // logvar cols 32..63
      *(float2*)&out[(size_t)NN * 32 + (size_t)i * 32 + (c0 - 32)] = acc;
    }
  }
}

// ---------------- batch-norm stats (S1, S2 per column of raw conv output) ----------------
__global__ __launch_bounds__(256) void k_bnstats(const float* __restrict__ h,
    float* __restrict__ stats) {
  __shared__ float s1[256], s2[256];
  int t = threadIdx.x, c = t & 63, rg = t >> 6;
  float a1 = 0.f, a2 = 0.f;
  for (int row = blockIdx.x * 4 + rg; row < NN; row += gridDim.x * 4) {
    float v = h[(size_t)row * 64 + c];
    a1 += v; a2 += v * v;
  }
  s1[t] = a1; s2[t] = a2; __syncthreads();
  if (rg == 0) {
    a1 = s1[c] + s1[64 + c] + s1[128 + c] + s1[192 + c];
    a2 = s2[c] + s2[64 + c] + s2[128 + c] + s2[192 + c];
    atomicAdd(&stats[c], a1);
    atomicAdd(&stats[64 + c], a2);
  }
}

extern "C" void kernel_launch(void* const* d_in, const int* in_sizes, int n_in,
                              void* d_out, int out_size, void* d_ws, size_t ws_size,
                              hipStream_t stream) {
  (void)in_sizes; (void)n_in; (void)out_size; (void)ws_size;
  const float* x    = (const float*)d_in[0];
  const int*   ei   = (const int*)d_in[1];
  const float* ew   = (const float*)d_in[2];
  const float* W_in = (const float*)d_in[3];
  const float* b_in = (const float*)d_in[4];
  const float* W1   = (const float*)d_in[5];
  const float* b1   = (const float*)d_in[6];
  const float* W2   = (const float*)d_in[7];
  const float* b2   = (const float*)d_in[8];
  const float* Wmu  = (const float*)d_in[9];
  const float* bmu  = (const float*)d_in[10];
  const float* Wlv  = (const float*)d_in[11];
  const float* blv  = (const float*)d_in[12];
  const float* g1   = (const float*)d_in[13];
  const float* be1  = (const float*)d_in[14];
  const float* g2   = (const float*)d_in[15];
  const float* be2  = (const float*)d_in[16];
  const int* src = ei;
  const int* dst = ei + NE;
  float* out = (float*)d_out;

  // workspace carve-up (256B aligned slices)
  char* p = (char*)d_ws;
  auto carve = [&](size_t bytes) { void* r = (void*)p; p += (bytes + 255) & ~(size_t)255; return r; };
  float* A      = (float*)carve((size_t)NN * 64 * 4);
  float* B      = (float*)carve((size_t)NN * 64 * 4);
  unsigned long long* packed = (unsigned long long*)carve((size_t)NN * 8);
  float* dinv   = (float*)carve((size_t)NN * 4);
  int*   cnt    = (int*)carve((size_t)NN * 4);
  int*   indptr = (int*)carve((size_t)(NN + 1) * 4);
  unsigned char* rank = (unsigned char*)carve((size_t)NE);
  int2*  edges  = (int2*)carve((size_t)NE * 8);        // packed (src, coef)
  int*   bsum   = (int*)carve(512 * 4);
  int*   boff   = (int*)carve(512 * 4);
  float* stats1 = (float*)carve(128 * 4);
  float* stats2 = (float*)carve(128 * 4);

  const int nbE = (NE + 255) / 256;     // 6250
  const int nbN = (NN + 255) / 256;     // 391
  const int gLin128 = (NN + 31) / 32;   // 3125
  const int gLin64  = (NN + 63) / 64;   // 1563
  const int gWave2  = ((NN + 1) / 2 * 64 + 255) / 256;  // 12500 (2 nodes/wave)

  // ---- graph preprocessing (identical every call) ----
  hipMemsetAsync(packed, 0, (size_t)NN * 8, stream);
  k_degpack<<<nbE, 256, 0, stream>>>(dst, ew, packed, rank);
  k_unpack<<<nbN, 256, 0, stream>>>(packed, dinv, cnt);
  k_scan1<<<nbN, 256, 0, stream>>>(cnt, indptr, bsum);
  k_scan2<<<1, 512, 0, stream>>>(bsum, boff, nbN);
  k_scan3<<<nbN, 256, 0, stream>>>(indptr, boff);
  k_fill<<<nbE, 256, 0, stream>>>(src, dst, ew, dinv, indptr, rank, edges);

  // ---- h0 = x @ W_in + b_in ----
  k_lin<128, 2, false><<<gLin128, 256, 0, stream>>>(x, W_in, b_in, nullptr, nullptr, nullptr, A);
  // ---- conv1 ----
  k_lin<64, 4, false><<<gLin64, 256, 0, stream>>>(A, W1, b1, nullptr, nullptr, nullptr, B);
  k_gather2<false><<<gWave2, 256, 0, stream>>>((const float2*)B, dinv, indptr, edges, A);
  hipMemsetAsync(stats1, 0, 128 * 4, stream);
  k_bnstats<<<256, 256, 0, stream>>>(A, stats1);
  // ---- conv2 (BN1+ReLU fused into lin's staging) ----
  k_lin<64, 4, true><<<gLin64, 256, 0, stream>>>(A, W2, b2, stats1, g1, be1, B);
  k_gather2<false><<<gWave2, 256, 0, stream>>>((const float2*)B, dinv, indptr, edges, A);
  hipMemsetAsync(stats2, 0, 128 * 4, stream);
  k_bnstats<<<256, 256, 0, stream>>>(A, stats2);
  // ---- mu / logvar (BN2+ReLU fused, 64-wide payload) ----
  k_linz<<<gLin64, 256, 0, stream>>>(A, Wmu, bmu, Wlv, blv, stats2, g2, be2, B);
  k_gather2<true><<<gWave2, 256, 0, stream>>>((const float2*)B, dinv, indptr, edges, out);
}

// Round 11
// 497.390 us; speedup vs baseline: 2.0579x; 1.2315x over previous
//
#include <hip/hip_runtime.h>

#define NN 100000
#define NE 1600000

__device__ __forceinline__ float b2f(unsigned short u) {
  return __uint_as_float(((unsigned)u) << 16);
}
__device__ __forceinline__ unsigned short f2bf(float f) {
  unsigned u = __float_as_uint(f);
  u += 0x7fffu + ((u >> 16) & 1u);
  return (unsigned short)(u >> 16);
}

// ---------------- packed degree+count histogram: one returning u64 atomic per edge ----
__global__ __launch_bounds__(256) void k_degpack(const int* __restrict__ dst,
    const float* __restrict__ ew, unsigned long long* __restrict__ packed,
    unsigned char* __restrict__ rank) {
  int e = blockIdx.x * 256 + threadIdx.x;
  if (e < NE) {
    int d = dst[e];
    unsigned long long rec = (1ULL << 40) |
        (unsigned long long)__float2uint_rn(ew[e] * 16777216.0f);
    unsigned long long old = atomicAdd(&packed[d], rec);
    rank[e] = (unsigned char)(old >> 40);
  }
}

__global__ __launch_bounds__(256) void k_unpack(const unsigned long long* __restrict__ packed,
    float* __restrict__ dinv, int* __restrict__ cnt) {
  int i = blockIdx.x * 256 + threadIdx.x;
  if (i < NN) {
    unsigned long long v = packed[i];
    cnt[i] = (int)(v >> 40);
    float deg = (float)(v & ((1ULL << 40) - 1)) * (1.0f / 16777216.0f);
    dinv[i] = rsqrtf(deg + 1.0f);
  }
}

// ---------------- 3-kernel exclusive scan (counts -> indptr) ----------------
__global__ __launch_bounds__(256) void k_scan1(const int* __restrict__ cnt,
    int* __restrict__ indptr, int* __restrict__ bsum) {
  __shared__ int sd[256];
  int t = threadIdx.x, i = blockIdx.x * 256 + t;
  int v = (i < NN) ? cnt[i] : 0;
  sd[t] = v; __syncthreads();
  #pragma unroll
  for (int o = 1; o < 256; o <<= 1) {
    int x = (t >= o) ? sd[t - o] : 0;
    __syncthreads(); sd[t] += x; __syncthreads();
  }
  if (i < NN) indptr[i] = sd[t] - v;
  if (t == 255) bsum[blockIdx.x] = sd[255];
}

__global__ __launch_bounds__(512) void k_scan2(const int* __restrict__ bsum,
    int* __restrict__ boff, int nb) {
  __shared__ int sd[512];
  int t = threadIdx.x;
  int v = (t < nb) ? bsum[t] : 0;
  sd[t] = v; __syncthreads();
  #pragma unroll
  for (int o = 1; o < 512; o <<= 1) {
    int x = (t >= o) ? sd[t - o] : 0;
    __syncthreads(); sd[t] += x; __syncthreads();
  }
  if (t < nb) boff[t] = sd[t] - v;
}

__global__ __launch_bounds__(256) void k_scan3(int* __restrict__ indptr,
    const int* __restrict__ boff) {
  int i = blockIdx.x * 256 + threadIdx.x;
  if (i < NN) {
    indptr[i] = indptr[i] + boff[i >> 8];
  } else if (i == NN) {
    indptr[NN] = NE;
  }
}

// ---------------- CSR fill: deterministic position, NO atomics ----------------
__global__ __launch_bounds__(256) void k_fill(const int* __restrict__ src,
    const int* __restrict__ dst, const float* __restrict__ ew,
    const float* __restrict__ dinv, const int* __restrict__ indptr,
    const unsigned char* __restrict__ rank, int2* __restrict__ edges) {
  int e = blockIdx.x * 256 + threadIdx.x;
  if (e < NE) {
    int s = src[e], d = dst[e];
    int p = indptr[d] + (int)rank[e];
    float coef = dinv[s] * dinv[d] * ew[e];
    edges[p] = make_int2(s, __float_as_int(coef));
  }
}

// ---------------- dense linear: out_bf16[N,64] = f(in)[N,K] @ W[K,64] + b ----------------
// BFIN: input is bf16. BN: f(x) = relu(x*scale[c]+shift[c]) from raw column stats.
template<int K, int RPT, bool BN, bool BFIN>
__global__ __launch_bounds__(256) void k_lin(const void* __restrict__ inv,
    const float* __restrict__ W, const float* __restrict__ bias,
    const float* __restrict__ stats, const float* __restrict__ g,
    const float* __restrict__ be, unsigned short* __restrict__ out) {
  constexpr int ROWS = 16 * RPT, RS = ROWS + 4;
  __shared__ __align__(16) float Wl[K * 64];
  __shared__ __align__(16) float rlT[K * RS];     // transposed row tile [k][r]
  __shared__ __align__(16) float bl[64];
  __shared__ float bnscale[BN ? 64 : 1], bnshift[BN ? 64 : 1];
  int t = threadIdx.x;
  int r0 = blockIdx.x * ROWS;
  for (int i = t; i < K * 64; i += 256) Wl[i] = W[i];
  if (t < 64) bl[t] = bias[t];
  if constexpr (BN) {
    if (t < 64) {
      const float invn = 1.0f / (float)NN;
      float m = stats[t] * invn;
      float v = stats[64 + t] * invn - m * m;
      float sc = g[t] * rsqrtf(v + 1e-5f);
      bnscale[t] = sc;
      bnshift[t] = be[t] - m * sc;
    }
    __syncthreads();
  }
  if constexpr (BFIN) {
    const unsigned short* in = (const unsigned short*)inv;
    for (int i = t; i < ROWS * (K / 4); i += 256) {   // ushort4 loads (8B)
      int r = i / (K / 4), k0 = (i % (K / 4)) * 4;
      int row = r0 + r;
      ushort4 u = (row < NN) ? *(const ushort4*)&in[(size_t)row * K + k0]
                             : make_ushort4(0, 0, 0, 0);
      float v0 = b2f(u.x), v1 = b2f(u.y), v2 = b2f(u.z), v3 = b2f(u.w);
      if constexpr (BN) {
        v0 = v0 * bnscale[k0] + bnshift[k0];         v0 = v0 > 0.f ? v0 : 0.f;
        v1 = v1 * bnscale[k0 + 1] + bnshift[k0 + 1]; v1 = v1 > 0.f ? v1 : 0.f;
        v2 = v2 * bnscale[k0 + 2] + bnshift[k0 + 2]; v2 = v2 > 0.f ? v2 : 0.f;
        v3 = v3 * bnscale[k0 + 3] + bnshift[k0 + 3]; v3 = v3 > 0.f ? v3 : 0.f;
      }
      rlT[(k0 + 0) * RS + r] = v0;
      rlT[(k0 + 1) * RS + r] = v1;
      rlT[(k0 + 2) * RS + r] = v2;
      rlT[(k0 + 3) * RS + r] = v3;
    }
  } else {
    const float* in = (const float*)inv;
    for (int i = t; i < ROWS * K; i += 256) {
      int r = i / K, k = i - r * K;
      int row = r0 + r;
      rlT[k * RS + r] = (row < NN) ? in[(size_t)row * K + k] : 0.f;
    }
  }
  __syncthreads();
  int tc = t & 15, tr = t >> 4;
  float4 bv = *(const float4*)&bl[tc * 4];
  float acc[RPT][4];
  #pragma unroll
  for (int j = 0; j < RPT; j++) { acc[j][0] = bv.x; acc[j][1] = bv.y; acc[j][2] = bv.z; acc[j][3] = bv.w; }
  for (int k = 0; k < K; k++) {
    float4 wv = *(const float4*)&Wl[k * 64 + tc * 4];
    float rv[RPT];
    if constexpr (RPT == 4) {
      float4 r4 = *(const float4*)&rlT[k * RS + tr * 4];
      rv[0] = r4.x; rv[1] = r4.y; rv[2] = r4.z; rv[3] = r4.w;
    } else {
      float2 r2 = *(const float2*)&rlT[k * RS + tr * 2];
      rv[0] = r2.x; rv[1] = r2.y;
    }
    #pragma unroll
    for (int j = 0; j < RPT; j++) {
      acc[j][0] += rv[j] * wv.x;
      acc[j][1] += rv[j] * wv.y;
      acc[j][2] += rv[j] * wv.z;
      acc[j][3] += rv[j] * wv.w;
    }
  }
  #pragma unroll
  for (int j = 0; j < RPT; j++) {
    int row = r0 + tr * RPT + j;
    if (row < NN) {
      ushort4 o = make_ushort4(f2bf(acc[j][0]), f2bf(acc[j][1]),
                               f2bf(acc[j][2]), f2bf(acc[j][3]));
      *(ushort4*)&out[(size_t)row * 64 + tc * 4] = o;
    }
  }
}

// ---------------- linz: cols 0..31 = f(in)@Wmu+bmu, 32..63 = f(in)@Wlv+blv (bf16 io) ----
__global__ __launch_bounds__(256) void k_linz(const unsigned short* __restrict__ in,
    const float* __restrict__ Wmu, const float* __restrict__ bmu,
    const float* __restrict__ Wlv, const float* __restrict__ blv,
    const float* __restrict__ stats, const float* __restrict__ g,
    const float* __restrict__ be, unsigned short* __restrict__ out) {
  constexpr int K = 64, RPT = 4, ROWS = 64, RS = 68;
  __shared__ __align__(16) float Wl[K * 64];
  __shared__ __align__(16) float rlT[K * RS];
  __shared__ __align__(16) float bl[64];
  __shared__ float bnscale[64], bnshift[64];
  int t = threadIdx.x;
  int r0 = blockIdx.x * ROWS;
  for (int i = t; i < K * 64; i += 256) {
    int k = i >> 6, c = i & 63;
    Wl[i] = (c < 32) ? Wmu[k * 32 + c] : Wlv[k * 32 + c - 32];
  }
  if (t < 64) bl[t] = (t < 32) ? bmu[t] : blv[t - 32];
  if (t < 64) {
    const float invn = 1.0f / (float)NN;
    float m = stats[t] * invn;
    float v = stats[64 + t] * invn - m * m;
    float sc = g[t] * rsqrtf(v + 1e-5f);
    bnscale[t] = sc;
    bnshift[t] = be[t] - m * sc;
  }
  __syncthreads();
  for (int i = t; i < ROWS * 16; i += 256) {        // ushort4 loads
    int r = i / 16, k0 = (i & 15) * 4;
    int row = r0 + r;
    ushort4 u = (row < NN) ? *(const ushort4*)&in[(size_t)row * 64 + k0]
                           : make_ushort4(0, 0, 0, 0);
    float v0 = b2f(u.x) * bnscale[k0] + bnshift[k0];
    float v1 = b2f(u.y) * bnscale[k0 + 1] + bnshift[k0 + 1];
    float v2 = b2f(u.z) * bnscale[k0 + 2] + bnshift[k0 + 2];
    float v3 = b2f(u.w) * bnscale[k0 + 3] + bnshift[k0 + 3];
    rlT[(k0 + 0) * RS + r] = v0 > 0.f ? v0 : 0.f;
    rlT[(k0 + 1) * RS + r] = v1 > 0.f ? v1 : 0.f;
    rlT[(k0 + 2) * RS + r] = v2 > 0.f ? v2 : 0.f;
    rlT[(k0 + 3) * RS + r] = v3 > 0.f ? v3 : 0.f;
  }
  __syncthreads();
  int tc = t & 15, tr = t >> 4;
  float4 bv = *(const float4*)&bl[tc * 4];
  float acc[RPT][4];
  #pragma unroll
  for (int j = 0; j < RPT; j++) { acc[j][0] = bv.x; acc[j][1] = bv.y; acc[j][2] = bv.z; acc[j][3] = bv.w; }
  for (int k = 0; k < K; k++) {
    float4 wv = *(const float4*)&Wl[k * 64 + tc * 4];
    float4 r4 = *(const float4*)&rlT[k * RS + tr * 4];
    float rv[4] = { r4.x, r4.y, r4.z, r4.w };
    #pragma unroll
    for (int j = 0; j < RPT; j++) {
      acc[j][0] += rv[j] * wv.x;
      acc[j][1] += rv[j] * wv.y;
      acc[j][2] += rv[j] * wv.z;
      acc[j][3] += rv[j] * wv.w;
    }
  }
  #pragma unroll
  for (int j = 0; j < RPT; j++) {
    int row = r0 + tr * RPT + j;
    if (row < NN) {
      ushort4 o = make_ushort4(f2bf(acc[j][0]), f2bf(acc[j][1]),
                               f2bf(acc[j][2]), f2bf(acc[j][3]));
      *(ushort4*)&out[(size_t)row * 64 + tc * 4] = o;
    }
  }
}

// ---------------- CSR gather, 4 nodes/wave, bf16 h, ushort4 lanes, unroll x8 ------------
// quarter q = lane>>4 -> node wid*4+q; sub = lane&15 owns features [4*sub, 4*sub+4).
template<bool FINAL>
__global__ __launch_bounds__(256) void k_gather4(const unsigned short* __restrict__ h,
    const float* __restrict__ dinv, const int* __restrict__ indptr,
    const int2* __restrict__ edges, void* __restrict__ outp) {
  int wid = (blockIdx.x * 256 + threadIdx.x) >> 6;
  int lane = threadIdx.x & 63;
  int q = lane >> 4, sub = lane & 15;
  int i = wid * 4 + q;
  if (i >= NN) return;
  int e0 = indptr[i], e1 = indptr[i + 1];
  float di = dinv[i], di2 = di * di;
  ushort4 hv = *(const ushort4*)&h[(size_t)i * 64 + sub * 4];
  float a0 = b2f(hv.x) * di2, a1 = b2f(hv.y) * di2;
  float a2 = b2f(hv.z) * di2, a3 = b2f(hv.w) * di2;
  int e = e0;
  for (; e + 8 <= e1; e += 8) {
    int2 r0 = edges[e],     r1 = edges[e + 1], r2 = edges[e + 2], r3 = edges[e + 3];
    int2 r4 = edges[e + 4], r5 = edges[e + 5], r6 = edges[e + 6], r7 = edges[e + 7];
    ushort4 v0 = *(const ushort4*)&h[(size_t)r0.x * 64 + sub * 4];
    ushort4 v1 = *(const ushort4*)&h[(size_t)r1.x * 64 + sub * 4];
    ushort4 v2 = *(const ushort4*)&h[(size_t)r2.x * 64 + sub * 4];
    ushort4 v3 = *(const ushort4*)&h[(size_t)r3.x * 64 + sub * 4];
    ushort4 v4 = *(const ushort4*)&h[(size_t)r4.x * 64 + sub * 4];
    ushort4 v5 = *(const ushort4*)&h[(size_t)r5.x * 64 + sub * 4];
    ushort4 v6 = *(const ushort4*)&h[(size_t)r6.x * 64 + sub * 4];
    ushort4 v7 = *(const ushort4*)&h[(size_t)r7.x * 64 + sub * 4];
    float c0 = __int_as_float(r0.y), c1 = __int_as_float(r1.y);
    float c2 = __int_as_float(r2.y), c3 = __int_as_float(r3.y);
    float c4 = __int_as_float(r4.y), c5 = __int_as_float(r5.y);
    float c6 = __int_as_float(r6.y), c7 = __int_as_float(r7.y);
    a0 += b2f(v0.x) * c0; a1 += b2f(v0.y) * c0; a2 += b2f(v0.z) * c0; a3 += b2f(v0.w) * c0;
    a0 += b2f(v1.x) * c1; a1 += b2f(v1.y) * c1; a2 += b2f(v1.z) * c1; a3 += b2f(v1.w) * c1;
    a0 += b2f(v2.x) * c2; a1 += b2f(v2.y) * c2; a2 += b2f(v2.z) * c2; a3 += b2f(v2.w) * c2;
    a0 += b2f(v3.x) * c3; a1 += b2f(v3.y) * c3; a2 += b2f(v3.z) * c3; a3 += b2f(v3.w) * c3;
    a0 += b2f(v4.x) * c4; a1 += b2f(v4.y) * c4; a2 += b2f(v4.z) * c4; a3 += b2f(v4.w) * c4;
    a0 += b2f(v5.x) * c5; a1 += b2f(v5.y) * c5; a2 += b2f(v5.z) * c5; a3 += b2f(v5.w) * c5;
    a0 += b2f(v6.x) * c6; a1 += b2f(v6.y) * c6; a2 += b2f(v6.z) * c6; a3 += b2f(v6.w) * c6;
    a0 += b2f(v7.x) * c7; a1 += b2f(v7.y) * c7; a2 += b2f(v7.z) * c7; a3 += b2f(v7.w) * c7;
  }
  for (; e < e1; e++) {
    int2 r = edges[e];
    ushort4 v = *(const ushort4*)&h[(size_t)r.x * 64 + sub * 4];
    float c = __int_as_float(r.y);
    a0 += b2f(v.x) * c; a1 += b2f(v.y) * c; a2 += b2f(v.z) * c; a3 += b2f(v.w) * c;
  }
  if (!FINAL) {
    unsigned short* out = (unsigned short*)outp;
    ushort4 o = make_ushort4(f2bf(a0), f2bf(a1), f2bf(a2), f2bf(a3));
    *(ushort4*)&out[(size_t)i * 64 + sub * 4] = o;
  } else {
    float* out = (float*)outp;
    float4 o = make_float4(a0, a1, a2, a3);
    if (sub < 8) {                                  // mu cols 0..31
      *(float4*)&out[(size_t)i * 32 + sub * 4] = o;
    } else {                                        // logvar cols 32..63
      *(float4*)&out[(size_t)NN * 32 + (size_t)i * 32 + (sub * 4 - 32)] = o;
    }
  }
}

// ---------------- batch-norm stats (S1, S2 per column of raw bf16 conv output) ---------
__global__ __launch_bounds__(256) void k_bnstats(const unsigned short* __restrict__ h,
    float* __restrict__ stats) {
  __shared__ float sh1[16][68], sh2[16][68];
  int t = threadIdx.x;
  int cg = (t & 15) * 4, rg = t >> 4;
  float s10 = 0.f, s11 = 0.f, s12 = 0.f, s13 = 0.f;
  float s20 = 0.f, s21 = 0.f, s22 = 0.f, s23 = 0.f;
  for (int row = blockIdx.x * 16 + rg; row < NN; row += gridDim.x * 16) {
    ushort4 u = *(const ushort4*)&h[(size_t)row * 64 + cg];
    float v0 = b2f(u.x), v1 = b2f(u.y), v2 = b2f(u.z), v3 = b2f(u.w);
    s10 += v0; s20 += v0 * v0;
    s11 += v1; s21 += v1 * v1;
    s12 += v2; s22 += v2 * v2;
    s13 += v3; s23 += v3 * v3;
  }
  sh1[rg][cg] = s10; sh1[rg][cg + 1] = s11; sh1[rg][cg + 2] = s12; sh1[rg][cg + 3] = s13;
  sh2[rg][cg] = s20; sh2[rg][cg + 1] = s21; sh2[rg][cg + 2] = s22; sh2[rg][cg + 3] = s23;
  __syncthreads();
  if (t < 64) {
    float a1 = 0.f, a2 = 0.f;
    #pragma unroll
    for (int r = 0; r < 16; r++) { a1 += sh1[r][t]; a2 += sh2[r][t]; }
    atomicAdd(&stats[t], a1);
    atomicAdd(&stats[64 + t], a2);
  }
}

extern "C" void kernel_launch(void* const* d_in, const int* in_sizes, int n_in,
                              void* d_out, int out_size, void* d_ws, size_t ws_size,
                              hipStream_t stream) {
  (void)in_sizes; (void)n_in; (void)out_size; (void)ws_size;
  const float* x    = (const float*)d_in[0];
  const int*   ei   = (const int*)d_in[1];
  const float* ew   = (const float*)d_in[2];
  const float* W_in = (const float*)d_in[3];
  const float* b_in = (const float*)d_in[4];
  const float* W1   = (const float*)d_in[5];
  const float* b1   = (const float*)d_in[6];
  const float* W2   = (const float*)d_in[7];
  const float* b2   = (const float*)d_in[8];
  const float* Wmu  = (const float*)d_in[9];
  const float* bmu  = (const float*)d_in[10];
  const float* Wlv  = (const float*)d_in[11];
  const float* blv  = (const float*)d_in[12];
  const float* g1   = (const float*)d_in[13];
  const float* be1  = (const float*)d_in[14];
  const float* g2   = (const float*)d_in[15];
  const float* be2  = (const float*)d_in[16];
  const int* src = ei;
  const int* dst = ei + NE;
  float* out = (float*)d_out;

  // workspace carve-up (256B aligned slices)
  char* p = (char*)d_ws;
  auto carve = [&](size_t bytes) { void* r = (void*)p; p += (bytes + 255) & ~(size_t)255; return r; };
  unsigned short* A = (unsigned short*)carve((size_t)NN * 64 * 2);   // bf16
  unsigned short* B = (unsigned short*)carve((size_t)NN * 64 * 2);   // bf16
  unsigned long long* packed = (unsigned long long*)carve((size_t)NN * 8);
  float* dinv   = (float*)carve((size_t)NN * 4);
  int*   cnt    = (int*)carve((size_t)NN * 4);
  int*   indptr = (int*)carve((size_t)(NN + 1) * 4);
  unsigned char* rank = (unsigned char*)carve((size_t)NE);
  int2*  edges  = (int2*)carve((size_t)NE * 8);
  int*   bsum   = (int*)carve(512 * 4);
  int*   boff   = (int*)carve(512 * 4);
  float* stats1 = (float*)carve(128 * 4);
  float* stats2 = (float*)carve(128 * 4);

  const int nbE = (NE + 255) / 256;     // 6250
  const int nbN = (NN + 255) / 256;     // 391
  const int gLin128 = (NN + 31) / 32;   // 3125
  const int gLin64  = (NN + 63) / 64;   // 1563
  const int gWave4  = (NN + 15) / 16;   // 6250 (4 nodes/wave, 4 waves/block)

  // ---- graph preprocessing (identical every call) ----
  hipMemsetAsync(packed, 0, (size_t)NN * 8, stream);
  k_degpack<<<nbE, 256, 0, stream>>>(dst, ew, packed, rank);
  k_unpack<<<nbN, 256, 0, stream>>>(packed, dinv, cnt);
  k_scan1<<<nbN, 256, 0, stream>>>(cnt, indptr, bsum);
  k_scan2<<<1, 512, 0, stream>>>(bsum, boff, nbN);
  k_scan3<<<nbN, 256, 0, stream>>>(indptr, boff);
  k_fill<<<nbE, 256, 0, stream>>>(src, dst, ew, dinv, indptr, rank, edges);

  // ---- h0 = x @ W_in + b_in  (fp32 in -> bf16 out) ----
  k_lin<128, 2, false, false><<<gLin128, 256, 0, stream>>>(x, W_in, b_in, nullptr, nullptr, nullptr, A);
  // ---- conv1 ----
  k_lin<64, 4, false, true><<<gLin64, 256, 0, stream>>>(A, W1, b1, nullptr, nullptr, nullptr, B);
  k_gather4<false><<<gWave4, 256, 0, stream>>>(B, dinv, indptr, edges, A);
  hipMemsetAsync(stats1, 0, 128 * 4, stream);
  k_bnstats<<<256, 256, 0, stream>>>(A, stats1);
  // ---- conv2 (BN1+ReLU fused into lin staging) ----
  k_lin<64, 4, true, true><<<gLin64, 256, 0, stream>>>(A, W2, b2, stats1, g1, be1, B);
  k_gather4<false><<<gWave4, 256, 0, stream>>>(B, dinv, indptr, edges, A);
  hipMemsetAsync(stats2, 0, 128 * 4, stream);
  k_bnstats<<<256, 256, 0, stream>>>(A, stats2);
  // ---- mu / logvar (BN2+ReLU fused, 64-wide payload; final gather writes fp32) ----
  k_linz<<<gLin64, 256, 0, stream>>>(A, Wmu, bmu, Wlv, blv, stats2, g2, be2, B);
  k_gather4<true><<<gWave4, 256, 0, stream>>>(B, dinv, indptr, edges, out);
}